// Round 17
// baseline (180.577 us; speedup 1.0000x reference)
//
#include <hip/hip_runtime.h>
#include <hip/hip_fp16.h>
#include <math.h>

#define HW    2304      // 48*48
#define NPOS  442368    // 192*48*48

typedef _Float16 f16x8 __attribute__((ext_vector_type(8)));
typedef __fp16   h16x2 __attribute__((ext_vector_type(2)));
typedef float    f32x4 __attribute__((ext_vector_type(4)));

__device__ __forceinline__ float phi_f(float z) {
    return 0.5f * (1.0f + erff(z * 0.70710678118654752f));
}
__device__ __forceinline__ unsigned short f2h(float v) {
    _Float16 h = (_Float16)v;
    return *reinterpret_cast<unsigned short*>(&h);
}
__device__ __forceinline__ unsigned int pk2(float a, float b) {
    return (unsigned int)f2h(a) | ((unsigned int)f2h(b) << 16);
}
__device__ __forceinline__ unsigned int pkrtz(float a, float b) {
    h16x2 h = __builtin_amdgcn_cvt_pkrtz(a, b);
    return *reinterpret_cast<unsigned int*>(&h);
}

// ---------------- prep_all: hyperTp transpose + apack + pk + xhp ---------------
__global__ __launch_bounds__(256) void prep_all(const float* __restrict__ hyper,
                                                const float* __restrict__ W3,
                                                const float* __restrict__ W1,
                                                const float* __restrict__ Wa,
                                                const float* __restrict__ ba,
                                                const float* __restrict__ b1,
                                                const float* __restrict__ Wb,
                                                const float* __restrict__ bb,
                                                const float* __restrict__ Wc,
                                                const float* __restrict__ xg,
                                                unsigned short* __restrict__ hyperTp,
                                                unsigned short* __restrict__ apack,
                                                unsigned short* __restrict__ pk,
                                                unsigned short* __restrict__ xhp) {
    const int bx = blockIdx.x;
    if (bx < 948) {                        // ---- hyperTp (948 = 79 x 12)
        __shared__ float s[32][33];
        const int pt = bx % 79, it = bx / 79;
        const int tid = threadIdx.x;
        const int c = tid & 31, r = tid >> 5;
        const int pp = pt * 32 + c;
        const int yp = pp / 50, xp = pp % 50;
        const bool inter = (pp < 2500) && yp >= 1 && yp <= 48 && xp >= 1 && xp <= 48;
        const int src = inter ? ((yp - 1) * 48 + (xp - 1)) : 0;
#pragma unroll
        for (int i = 0; i < 4; ++i) {
            int icl = r + i * 8;
            s[icl][c] = inter ? hyper[(size_t)(it * 32 + icl) * HW + src] : 0.f;
        }
        __syncthreads();
#pragma unroll
        for (int i = 0; i < 4; ++i) {
            int pl = r + i * 8;
            int pp2 = pt * 32 + pl;
            if (pp2 < 2500)
                hyperTp[(size_t)pp2 * 384 + it * 32 + c] = f2h(s[c][pl]);
        }
    } else if (bx < 3540) {                // ---- apack
        int idx = (bx - 948) * 256 + threadIdx.x;  // 663552 total
        int j = idx & 7;
        int l = (idx >> 3) & 63;
        int rest = idx >> 9;
        int t = rest % 9; rest /= 9;
        int c = rest % 12; int T = rest / 12;
        int oc = T * 16 + (l & 15);
        int ic = c * 32 + (l >> 4) * 8 + j;
        apack[idx] = f2h(W3[((size_t)oc * 384 + ic) * 9 + t]);
    } else if (bx < 3700) {                // ---- pk
        int idx = (bx - 3540) * 256 + threadIdx.x;
        if (idx >= 40960) return;
        float v = 0.f;
        if (idx < 31744) {
            int j = idx & 7, lane = (idx >> 3) & 63, s = (idx >> 9) & 1, c = idx >> 10;
            int q = lane >> 4;
            int oc = s * 16 + (lane & 15);
            int r = 2 * c + (q >> 1), h = q & 1, kw = 8 * h + j;
            if (oc < 24 && r < 61 && kw < 11) {
                int kd = r / 11, kh = r % 11;
                int tap = kd * 121 + kh * 11 + kw;
                if (tap < 665) v = W1[oc * 1331 + tap];
            }
        } else if (idx < 33280) {
            int i2 = idx - 31744;
            int j = i2 & 7, lane = (i2 >> 3) & 63, t = i2 >> 9;
            int m = t * 16 + (lane & 15), k = (lane >> 4) * 8 + j;
            if (k < 25) v = Wa[m * 25 + k];
            else if (k == 25) {
                float s = ba[m];
                for (int c = 0; c < 24; ++c) s += Wa[m * 25 + c] * b1[c];
                v = s;
            }
        } else if (idx < 39424) {
            int i3 = idx - 33280;
            int j = i3 & 7, lane = (i3 >> 3) & 63, k2 = (i3 >> 9) & 1, s = i3 >> 10;
            int m = s * 16 + (lane & 15), ch = k2 * 32 + (lane >> 4) * 8 + j;
            if (ch < 48) v = Wb[m * 48 + ch];
            else if (ch == 48) v = bb[m];
        } else {
            int i4 = idx - 39424;
            int j = i4 & 7, lane = (i4 >> 3) & 63, k3 = i4 >> 9;
            int m = lane & 15, ch = k3 * 32 + (lane >> 4) * 8 + j;
            if (m < 9) v = Wc[m * 96 + ch];
        }
        pk[idx] = f2h(v);
    } else {                               // ---- xhp
        int idx = (bx - 3700) * 256 + threadIdx.x;   // 187456 uint2
        if (idx >= 187456) return;
        int si = idx * 4;
        int zp = si / 3712, rem = si - zp * 3712;
        int yp = rem >> 6, xp0 = rem & 63;
        float f[4];
#pragma unroll
        for (int k = 0; k < 4; ++k) {
            int xp = xp0 + k;
            bool in = zp >= 5 && zp < 197 && yp >= 5 && yp < 53 && xp >= 5 && xp < 53;
            f[k] = in ? xg[(size_t)(zp - 5) * HW + (yp - 5) * 48 + (xp - 5)] : 0.f;
        }
        *(uint2*)&xhp[si] = make_uint2(pk2(f[0], f[1]), pk2(f[2], f[3]));
    }
}

// ---------------- conv2d: barrier-free LDS-free implicit GEMM ------------------
__global__ __launch_bounds__(256) void conv2d_mfma(const unsigned short* __restrict__ hyperTp,
                                                   const unsigned short* __restrict__ apack,
                                                   const float* __restrict__ b3,
                                                   float* __restrict__ hbuf) {
    const int T = blockIdx.x;
    const int tid = threadIdx.x, w = tid >> 6, lane = tid & 63;
    const int n = lane & 15, q = lane >> 4;
    const int g = blockIdx.y * 4 + w;         // 0..143
    const int yy = g / 3, xb = (g % 3) * 16;
    const size_t base = (size_t)(yy * 50 + xb + n) * 384 + q * 8;

    f32x4 acc = {};
    for (int c = 0; c < 12; ++c) {
        const unsigned short* ap = apack + ((size_t)(T * 12 + c) * 9) * 512 + lane * 8;
        const int coff = c * 32;
#pragma unroll
        for (int t = 0; t < 9; ++t) {
            f16x8 a = *(const f16x8*)(ap + t * 512);
            const int dd = (t / 3) * 50 + (t % 3);
            f16x8 b = *(const f16x8*)(hyperTp + base + (size_t)dd * 384 + coff);
            acc = __builtin_amdgcn_mfma_f32_16x16x32_f16(a, b, acc, 0, 0, 0);
        }
    }
#pragma unroll
    for (int e = 0; e < 4; ++e) {
        int oc = T * 16 + q * 4 + e;
        hbuf[(size_t)oc * HW + yy * 48 + xb + n] = acc[e] + b3[oc];
    }
}

// ---------------- conv3d + MLP + likelihood, fused, x-major blocks -------------
// grid (3,48,12) = 1728 blocks x 256 thr (4 waves); block: 16 x, 1 y, 16 d.
// LDS 31.8 KB (t1/t2/oac share one per-wave sequential scratch) -> 5 blocks/CU,
// 20 waves/CU (was 12): more cross-wave MFMA/VALU overlap for the VALU-bound loop.
#define PSTR 40
__global__ __launch_bounds__(256) void conv3d_mlp(const unsigned short* __restrict__ xhp,
                                                  const unsigned short* __restrict__ pk,
                                                  const float* __restrict__ hbuf,
                                                  const float* __restrict__ xg,
                                                  const float* __restrict__ bc,
                                                  float* __restrict__ out) {
    __shared__ __align__(16) unsigned char smem[31792];
    unsigned short* P = (unsigned short*)smem;              // patch 231*40*2 = 18480 B
    unsigned short* S = (unsigned short*)smem;              // 17408 B (post-barrier)
    const int tid = threadIdx.x, w = tid >> 6, lane = tid & 63;
    const int n = lane & 15, q = lane >> 4;
    const int x0 = blockIdx.x * 16, y0 = blockIdx.y, d0 = blockIdx.z * 16;
    // per-wave sequential scratch (3328 B): t1 (16x72), then t2 (16x104) overlays
    // it, then oacs (16x13 f32) overlays again — all program-ordered within a wave.
    unsigned short* tw = (unsigned short*)(smem + 18480) + w * 1664;
    unsigned short* t1s = tw;       // stride 72
    unsigned short* t2s = tw;       // stride 104
    float*          oacs = (float*)tw;  // stride 13

    // ---- stage patch: 231 rows (py*21+pz) x 32 shorts = 924 uint4 ----
#pragma unroll
    for (int k = 0; k < 4; ++k) {
        int idx = tid + k * 256;
        if (idx < 924) {
            int row = idx >> 2, quarter = idx & 3;
            int py = row / 21, pz = row - py * 21;
            const uint4* src = (const uint4*)(xhp + ((size_t)(d0 + pz) * 58 + (y0 + py)) * 64
                                              + x0 + quarter * 8);
            *(uint4*)&P[row * PSTR + quarter * 8] = *src;
        }
    }
    __syncthreads();

    // ---- conv3d K-loop (per-wave x-shift 4w) ----
    const f32x4 zf = {0.f, 0.f, 0.f, 0.f};
    f32x4 acc[4][2];
#pragma unroll
    for (int p = 0; p < 4; ++p) { acc[p][0] = zf; acc[p][1] = zf; }

    const f16x8* Av = (const f16x8*)pk;
    f16x8 a0 = Av[lane], a1 = Av[64 + lane];
    for (int c = 0; c < 31; ++c) {
        f16x8 ca0 = a0, ca1 = a1;
        int cn = (c < 30) ? c + 1 : 30;
        a0 = Av[cn * 128 + lane];
        a1 = Av[cn * 128 + 64 + lane];
        int r = 2 * c + (q >> 1);
        int kd = r / 11, kh = r - kd * 11;
        const unsigned short* rowp = P + (kh * 21 + (n + kd)) * PSTR + 4 * w + (q & 1) * 8;
        unsigned int u[6];
        *(uint2*)&u[0] = *(const uint2*)(rowp);
        *(uint2*)&u[2] = *(const uint2*)(rowp + 4);
        *(uint2*)&u[4] = *(const uint2*)(rowp + 8);
#pragma unroll
        for (int px = 0; px < 4; ++px) {
            unsigned int bw[4];
#pragma unroll
            for (int i = 0; i < 4; ++i) {
                if ((px & 1) == 0) bw[i] = u[(px >> 1) + i];
                else bw[i] = (u[(px >> 1) + i] >> 16) | (u[(px >> 1) + 1 + i] << 16);
            }
            f16x8 bf = *(f16x8*)bw;
            acc[px][0] = __builtin_amdgcn_mfma_f32_16x16x32_f16(ca0, bf, acc[px][0], 0, 0, 0);
            acc[px][1] = __builtin_amdgcn_mfma_f32_16x16x32_f16(ca1, bf, acc[px][1], 0, 0, 0);
        }
    }
    __syncthreads();   // all patch reads done; S overlays patch region

    // ---- stage t0 into S: row = w*16 + depth(n), col = px*32 + ch ----
#pragma unroll
    for (int px = 0; px < 4; ++px) {
        unsigned int lo = pk2(acc[px][0][0], acc[px][0][1]);
        unsigned int hi = pk2(acc[px][0][2], acc[px][0][3]);
        *(uint2*)&S[(w * 16 + n) * 136 + px * 32 + q * 4] = make_uint2(lo, hi);   // ch 0..15
        if (q < 2) {
            unsigned int l2 = pk2(acc[px][1][0], acc[px][1][1]);
            unsigned int h2 = pk2(acc[px][1][2], acc[px][1][3]);
            *(uint2*)&S[(w * 16 + n) * 136 + px * 32 + 16 + q * 4] = make_uint2(l2, h2); // 16..23
        }
    }
    // ch24 = h, ch25 = 1.0, ch26..31 = 0 ; lane -> (pxl = lane>>4, dep = lane&15)
    {
        const int pxl = lane >> 4, dep = lane & 15;
        float hv = hbuf[(size_t)(d0 + dep) * HW + y0 * 48 + x0 + 4 * w + pxl];
        *(uint4*)&S[(w * 16 + dep) * 136 + pxl * 32 + 24] =
            make_uint4(pk2(hv, 1.0f), 0u, 0u, 0u);
    }

    // ---- MLP weights into registers ----
    const f16x8* WaF = (const f16x8*)(pk + 31744);
    const f16x8* WbF = (const f16x8*)(pk + 33280);
    const f16x8* WcF = (const f16x8*)(pk + 39424);
    f16x8 waf[3], wbf[12], wcf[3];
#pragma unroll
    for (int s = 0; s < 3; ++s) waf[s] = WaF[s * 64 + lane];
#pragma unroll
    for (int t = 0; t < 12; ++t) wbf[t] = WbF[t * 64 + lane];
#pragma unroll
    for (int k = 0; k < 3; ++k) wcf[k] = WcF[k * 64 + lane];
    float bcv[4];
#pragma unroll
    for (int e = 0; e < 4; ++e) bcv[e] = (q * 4 + e < 9) ? bc[q * 4 + e] : 0.f;

    // ---- MLP + likelihood, one px (16 depths) at a time ----
#pragma unroll
    for (int px = 0; px < 4; ++px) {
        f16x8 b0 = *(const f16x8*)&S[(w * 16 + n) * 136 + px * 32 + q * 8];
        // t1 const channel (ch48 = 1.0) + zero pad ch49..63 (t2/oac overlaid it)
        {
            unsigned int lo = (q == 0) ? 0x00003C00u : 0u;
            *(uint2*)&t1s[n * 72 + 48 + q * 4] = make_uint2(lo, 0u);
        }
        // layer a: 26(+pad)->48
#pragma unroll
        for (int s = 0; s < 3; ++s) {
            f32x4 r1 = __builtin_amdgcn_mfma_f32_16x16x32_f16(waf[s], b0, zf, 0, 0, 0);
            *(uint2*)&t1s[n * 72 + s * 16 + q * 4] =
                make_uint2(pkrtz(fmaxf(r1[0], 0.f), fmaxf(r1[1], 0.f)),
                           pkrtz(fmaxf(r1[2], 0.f), fmaxf(r1[3], 0.f)));
        }
        // layer b: 48(+const)->96  (rb fully accumulated before t2 overwrites t1)
        f32x4 rb[6];
#pragma unroll
        for (int s = 0; s < 6; ++s) rb[s] = zf;
#pragma unroll
        for (int k2 = 0; k2 < 2; ++k2) {
            f16x8 bf = *(const f16x8*)&t1s[n * 72 + k2 * 32 + q * 8];
#pragma unroll
            for (int s = 0; s < 6; ++s)
                rb[s] = __builtin_amdgcn_mfma_f32_16x16x32_f16(wbf[s * 2 + k2], bf, rb[s], 0, 0, 0);
        }
#pragma unroll
        for (int s = 0; s < 6; ++s)
            *(uint2*)&t2s[n * 104 + s * 16 + q * 4] =
                make_uint2(pkrtz(fmaxf(rb[s][0], 0.f), fmaxf(rb[s][1], 0.f)),
                           pkrtz(fmaxf(rb[s][2], 0.f), fmaxf(rb[s][3], 0.f)));
        // layer c: 96->9
        f32x4 rc = zf;
#pragma unroll
        for (int k3 = 0; k3 < 3; ++k3) {
            f16x8 bf = *(const f16x8*)&t2s[n * 104 + k3 * 32 + q * 8];
            rc = __builtin_amdgcn_mfma_f32_16x16x32_f16(wcf[k3], bf, rc, 0, 0, 0);
        }
        // oacs overlays t2 (reads done above, same-wave order)
#pragma unroll
        for (int e = 0; e < 4; ++e) {
            int row = q * 4 + e;
            if (row < 9) oacs[n * 13 + row] = rc[e] + bcv[e];
        }
        // likelihood: lanes 0..15, one depth each
        if (lane < 16) {
            float o[9];
#pragma unroll
            for (int jj = 0; jj < 9; ++jj) o[jj] = oacs[lane * 13 + jj];
            const size_t gp = (size_t)(d0 + lane) * HW + y0 * 48 + x0 + 4 * w + px;
            float xv = xg[gp];
            float m = fmaxf(o[6], fmaxf(o[7], o[8]));
            float e0 = expf(o[6] - m), e1 = expf(o[7] - m), e2 = expf(o[8] - m);
            float inv_es = 1.0f / (e0 + e1 + e2);
            float p = 0.f;
#pragma unroll
            for (int jj = 0; jj < 3; ++jj) {
                float mu = o[jj];
                float sc = o[3 + jj];
                sc = (sc == 0.0f) ? 1e-9f : sc;
                sc = fabsf(sc);
                float a = phi_f((xv + 0.5f - mu) / sc);
                float b = phi_f((xv - 0.5f - mu) / sc);
                float lik = fabsf(a - b);
                float wgt = ((jj == 0) ? e0 : (jj == 1) ? e1 : e2) * inv_es;
                p = fmaf(wgt, lik, p);
            }
            out[gp] = p;
#pragma unroll
            for (int jj = 0; jj < 9; ++jj) out[NPOS + (size_t)jj * NPOS + gp] = o[jj];
        }
    }
}

extern "C" void kernel_launch(void* const* d_in, const int* in_sizes, int n_in,
                              void* d_out, int out_size, void* d_ws, size_t ws_size,
                              hipStream_t stream) {
    const float* x     = (const float*)d_in[0];
    const float* hyper = (const float*)d_in[1];
    const float* W3    = (const float*)d_in[2];
    const float* b3    = (const float*)d_in[3];
    const float* W1    = (const float*)d_in[4];
    const float* b1    = (const float*)d_in[5];
    const float* Wa    = (const float*)d_in[6];
    const float* ba    = (const float*)d_in[7];
    const float* Wb    = (const float*)d_in[8];
    const float* bb    = (const float*)d_in[9];
    const float* Wc    = (const float*)d_in[10];
    const float* bc    = (const float*)d_in[11];
    float* out = (float*)d_out;

    float* hbuf = (float*)d_ws;                                // NPOS f32
    unsigned short* hyperTp = (unsigned short*)(hbuf + NPOS);  // 960000 f16
    unsigned short* apack   = hyperTp + 960000;                // 663552 f16
    unsigned short* pk      = apack + 663552;                  // 40960 f16
    unsigned short* xhp     = pk + 40960;                      // 749824 f16 (padded x)

    prep_all<<<4433, 256, 0, stream>>>(hyper, W3, W1, Wa, ba, b1, Wb, bb, Wc, x,
                                       hyperTp, apack, pk, xhp);
    conv2d_mfma<<<dim3(12, 36), 256, 0, stream>>>(hyperTp, apack, b3, hbuf);
    conv3d_mlp<<<dim3(3, 48, 12), 256, 0, stream>>>(xhp, pk, hbuf, x, bc, out);
}

// Round 18
// 177.268 us; speedup vs baseline: 1.0187x; 1.0187x over previous
//
#include <hip/hip_runtime.h>
#include <hip/hip_fp16.h>
#include <math.h>

#define HW    2304      // 48*48
#define NPOS  442368    // 192*48*48

typedef _Float16 f16x8 __attribute__((ext_vector_type(8)));
typedef __fp16   h16x2 __attribute__((ext_vector_type(2)));
typedef float    f32x4 __attribute__((ext_vector_type(4)));

__device__ __forceinline__ float phi_f(float z) {
    return 0.5f * (1.0f + erff(z * 0.70710678118654752f));
}
__device__ __forceinline__ unsigned short f2h(float v) {
    _Float16 h = (_Float16)v;
    return *reinterpret_cast<unsigned short*>(&h);
}
__device__ __forceinline__ unsigned int pk2(float a, float b) {
    return (unsigned int)f2h(a) | ((unsigned int)f2h(b) << 16);
}
__device__ __forceinline__ unsigned int pkrtz(float a, float b) {
    h16x2 h = __builtin_amdgcn_cvt_pkrtz(a, b);
    return *reinterpret_cast<unsigned int*>(&h);
}

// ---------------- prep_all: hyperTp transpose + apack + pk + xhp ---------------
__global__ __launch_bounds__(256) void prep_all(const float* __restrict__ hyper,
                                                const float* __restrict__ W3,
                                                const float* __restrict__ W1,
                                                const float* __restrict__ Wa,
                                                const float* __restrict__ ba,
                                                const float* __restrict__ b1,
                                                const float* __restrict__ Wb,
                                                const float* __restrict__ bb,
                                                const float* __restrict__ Wc,
                                                const float* __restrict__ xg,
                                                unsigned short* __restrict__ hyperTp,
                                                unsigned short* __restrict__ apack,
                                                unsigned short* __restrict__ pk,
                                                unsigned short* __restrict__ xhp) {
    const int bx = blockIdx.x;
    if (bx < 948) {                        // ---- hyperTp (948 = 79 x 12)
        __shared__ float s[32][33];
        const int pt = bx % 79, it = bx / 79;
        const int tid = threadIdx.x;
        const int c = tid & 31, r = tid >> 5;
        const int pp = pt * 32 + c;
        const int yp = pp / 50, xp = pp % 50;
        const bool inter = (pp < 2500) && yp >= 1 && yp <= 48 && xp >= 1 && xp <= 48;
        const int src = inter ? ((yp - 1) * 48 + (xp - 1)) : 0;
#pragma unroll
        for (int i = 0; i < 4; ++i) {
            int icl = r + i * 8;
            s[icl][c] = inter ? hyper[(size_t)(it * 32 + icl) * HW + src] : 0.f;
        }
        __syncthreads();
#pragma unroll
        for (int i = 0; i < 4; ++i) {
            int pl = r + i * 8;
            int pp2 = pt * 32 + pl;
            if (pp2 < 2500)
                hyperTp[(size_t)pp2 * 384 + it * 32 + c] = f2h(s[c][pl]);
        }
    } else if (bx < 3540) {                // ---- apack
        int idx = (bx - 948) * 256 + threadIdx.x;  // 663552 total
        int j = idx & 7;
        int l = (idx >> 3) & 63;
        int rest = idx >> 9;
        int t = rest % 9; rest /= 9;
        int c = rest % 12; int T = rest / 12;
        int oc = T * 16 + (l & 15);
        int ic = c * 32 + (l >> 4) * 8 + j;
        apack[idx] = f2h(W3[((size_t)oc * 384 + ic) * 9 + t]);
    } else if (bx < 3700) {                // ---- pk
        int idx = (bx - 3540) * 256 + threadIdx.x;
        if (idx >= 40960) return;
        float v = 0.f;
        if (idx < 31744) {
            int j = idx & 7, lane = (idx >> 3) & 63, s = (idx >> 9) & 1, c = idx >> 10;
            int q = lane >> 4;
            int oc = s * 16 + (lane & 15);
            int r = 2 * c + (q >> 1), h = q & 1, kw = 8 * h + j;
            if (oc < 24 && r < 61 && kw < 11) {
                int kd = r / 11, kh = r % 11;
                int tap = kd * 121 + kh * 11 + kw;
                if (tap < 665) v = W1[oc * 1331 + tap];
            }
        } else if (idx < 33280) {
            int i2 = idx - 31744;
            int j = i2 & 7, lane = (i2 >> 3) & 63, t = i2 >> 9;
            int m = t * 16 + (lane & 15), k = (lane >> 4) * 8 + j;
            if (k < 25) v = Wa[m * 25 + k];
            else if (k == 25) {
                float s = ba[m];
                for (int c = 0; c < 24; ++c) s += Wa[m * 25 + c] * b1[c];
                v = s;
            }
        } else if (idx < 39424) {
            int i3 = idx - 33280;
            int j = i3 & 7, lane = (i3 >> 3) & 63, k2 = (i3 >> 9) & 1, s = i3 >> 10;
            int m = s * 16 + (lane & 15), ch = k2 * 32 + (lane >> 4) * 8 + j;
            if (ch < 48) v = Wb[m * 48 + ch];
            else if (ch == 48) v = bb[m];
        } else {
            int i4 = idx - 39424;
            int j = i4 & 7, lane = (i4 >> 3) & 63, k3 = i4 >> 9;
            int m = lane & 15, ch = k3 * 32 + (lane >> 4) * 8 + j;
            if (m < 9) v = Wc[m * 96 + ch];
        }
        pk[idx] = f2h(v);
    } else {                               // ---- xhp
        int idx = (bx - 3700) * 256 + threadIdx.x;   // 187456 uint2
        if (idx >= 187456) return;
        int si = idx * 4;
        int zp = si / 3712, rem = si - zp * 3712;
        int yp = rem >> 6, xp0 = rem & 63;
        float f[4];
#pragma unroll
        for (int k = 0; k < 4; ++k) {
            int xp = xp0 + k;
            bool in = zp >= 5 && zp < 197 && yp >= 5 && yp < 53 && xp >= 5 && xp < 53;
            f[k] = in ? xg[(size_t)(zp - 5) * HW + (yp - 5) * 48 + (xp - 5)] : 0.f;
        }
        *(uint2*)&xhp[si] = make_uint2(pk2(f[0], f[1]), pk2(f[2], f[3]));
    }
}

// ---------------- conv3d + conv2d(split-K) + MLP + likelihood, one kernel ------
// grid (3,48,12) = 1728 blocks x 256 thr (4 waves); block: 16 x, 1 y, 16 d.
// conv2d's h for this block's (oc-tile=z, y, x-tile) maps bijectively onto the
// grid: zero redundancy. 108 (ic-chunk,tap) K-pairs split 27/wave, partials
// reduced via 4 KB LDS, scattered into S ch24 with b3 folded.
#define PSTR 40
__global__ __launch_bounds__(256) void conv3d_mlp(const unsigned short* __restrict__ xhp,
                                                  const unsigned short* __restrict__ pk,
                                                  const unsigned short* __restrict__ hyperTp,
                                                  const unsigned short* __restrict__ apack,
                                                  const float* __restrict__ b3,
                                                  const float* __restrict__ xg,
                                                  const float* __restrict__ bc,
                                                  float* __restrict__ out) {
    __shared__ __align__(16) unsigned char smem[31792];
    unsigned short* P = (unsigned short*)smem;              // patch 231*40*2 = 18480 B
    unsigned short* S = (unsigned short*)smem;              // 17408 B (post-barrier)
    const int tid = threadIdx.x, w = tid >> 6, lane = tid & 63;
    const int n = lane & 15, q = lane >> 4;
    const int x0 = blockIdx.x * 16, y0 = blockIdx.y, d0 = blockIdx.z * 16;
    const int T = blockIdx.z;
    // per-wave sequential scratch; first 4 KB doubles as conv2d partial buffer
    float* part = (float*)(smem + 18480);                   // [wp 4][lane 64][e 4]
    unsigned short* tw = (unsigned short*)(smem + 18480) + w * 1664;
    unsigned short* t1s = tw;       // stride 72
    unsigned short* t2s = tw;       // stride 104
    float*          oacs = (float*)tw;  // stride 13

    // ---- stage patch: 231 rows (py*21+pz) x 32 shorts = 924 uint4 ----
#pragma unroll
    for (int k = 0; k < 4; ++k) {
        int idx = tid + k * 256;
        if (idx < 924) {
            int row = idx >> 2, quarter = idx & 3;
            int py = row / 21, pz = row - py * 21;
            const uint4* src = (const uint4*)(xhp + ((size_t)(d0 + pz) * 58 + (y0 + py)) * 64
                                              + x0 + quarter * 8);
            *(uint4*)&P[row * PSTR + quarter * 8] = *src;
        }
    }
    __syncthreads();

    // ---- conv3d K-loop (per-wave x-shift 4w) ----
    const f32x4 zf = {0.f, 0.f, 0.f, 0.f};
    f32x4 acc[4][2];
#pragma unroll
    for (int p = 0; p < 4; ++p) { acc[p][0] = zf; acc[p][1] = zf; }

    const f16x8* Av = (const f16x8*)pk;
    f16x8 a0 = Av[lane], a1 = Av[64 + lane];
    for (int c = 0; c < 31; ++c) {
        f16x8 ca0 = a0, ca1 = a1;
        int cn = (c < 30) ? c + 1 : 30;
        a0 = Av[cn * 128 + lane];
        a1 = Av[cn * 128 + 64 + lane];
        int r = 2 * c + (q >> 1);
        int kd = r / 11, kh = r - kd * 11;
        const unsigned short* rowp = P + (kh * 21 + (n + kd)) * PSTR + 4 * w + (q & 1) * 8;
        unsigned int u[6];
        *(uint2*)&u[0] = *(const uint2*)(rowp);
        *(uint2*)&u[2] = *(const uint2*)(rowp + 4);
        *(uint2*)&u[4] = *(const uint2*)(rowp + 8);
#pragma unroll
        for (int px = 0; px < 4; ++px) {
            unsigned int bw[4];
#pragma unroll
            for (int i = 0; i < 4; ++i) {
                if ((px & 1) == 0) bw[i] = u[(px >> 1) + i];
                else bw[i] = (u[(px >> 1) + i] >> 16) | (u[(px >> 1) + 1 + i] << 16);
            }
            f16x8 bf = *(f16x8*)bw;
            acc[px][0] = __builtin_amdgcn_mfma_f32_16x16x32_f16(ca0, bf, acc[px][0], 0, 0, 0);
            acc[px][1] = __builtin_amdgcn_mfma_f32_16x16x32_f16(ca1, bf, acc[px][1], 0, 0, 0);
        }
    }

    // ---- conv2d split-K phase (global/L2 only): 27 (chunk,tap) pairs per wave --
    {
        const size_t base2 = (size_t)(y0 * 50 + x0 + n) * 384 + q * 8;
        f32x4 hacc = zf;
        for (int kk = 27 * w; kk < 27 * w + 27; ++kk) {
            int c2 = kk / 9, t2 = kk - c2 * 9;
            f16x8 a = *(const f16x8*)(apack + (((size_t)T * 12 + c2) * 9 + t2) * 512 + lane * 8);
            int dd = (t2 / 3) * 50 + (t2 % 3);
            f16x8 b = *(const f16x8*)(hyperTp + base2 + (size_t)dd * 384 + c2 * 32);
            hacc = __builtin_amdgcn_mfma_f32_16x16x32_f16(a, b, hacc, 0, 0, 0);
        }
        *(f32x4*)&part[(w * 64 + lane) * 4] = hacc;   // part[w][lane][e]
    }
    __syncthreads();   // #2: patch reads done (S may overlay) + partials visible

    // ---- stage t0 into S: row = w*16 + depth(n), col = px*32 + ch ----
#pragma unroll
    for (int px = 0; px < 4; ++px) {
        unsigned int lo = pk2(acc[px][0][0], acc[px][0][1]);
        unsigned int hi = pk2(acc[px][0][2], acc[px][0][3]);
        *(uint2*)&S[(w * 16 + n) * 136 + px * 32 + q * 4] = make_uint2(lo, hi);   // ch 0..15
        if (q < 2) {
            unsigned int l2 = pk2(acc[px][1][0], acc[px][1][1]);
            unsigned int h2 = pk2(acc[px][1][2], acc[px][1][3]);
            *(uint2*)&S[(w * 16 + n) * 136 + px * 32 + 16 + q * 4] = make_uint2(l2, h2); // 16..23
        }
    }
    // ---- h reduce + scatter: ch24 = conv2d + b3, ch25 = 1.0, ch26..31 = 0 ----
    // conv2d C/D layout: producer lane (n=px, q): acc[e] -> oc = T*16 + q*4+e.
    // consumer thread (wave w, lane): pl = lane>>4 (local px), dep = lane&15.
    {
        const int pl = lane >> 4, dep = lane & 15;
        const int p = 4 * w + pl;                   // global px in block
        const int lane_p = p + 16 * (dep >> 2), e = dep & 3;
        float hv = part[(0 * 64 + lane_p) * 4 + e] + part[(1 * 64 + lane_p) * 4 + e]
                 + part[(2 * 64 + lane_p) * 4 + e] + part[(3 * 64 + lane_p) * 4 + e];
        hv += b3[T * 16 + dep];
        *(uint4*)&S[(w * 16 + dep) * 136 + pl * 32 + 24] =
            make_uint4(pk2(hv, 1.0f), 0u, 0u, 0u);
    }
    __syncthreads();   // #3: partials consumed before MLP scratch (tw) overwrites

    // ---- MLP weights into registers ----
    const f16x8* WaF = (const f16x8*)(pk + 31744);
    const f16x8* WbF = (const f16x8*)(pk + 33280);
    const f16x8* WcF = (const f16x8*)(pk + 39424);
    f16x8 waf[3], wbf[12], wcf[3];
#pragma unroll
    for (int s = 0; s < 3; ++s) waf[s] = WaF[s * 64 + lane];
#pragma unroll
    for (int t = 0; t < 12; ++t) wbf[t] = WbF[t * 64 + lane];
#pragma unroll
    for (int k = 0; k < 3; ++k) wcf[k] = WcF[k * 64 + lane];
    float bcv[4];
#pragma unroll
    for (int e = 0; e < 4; ++e) bcv[e] = (q * 4 + e < 9) ? bc[q * 4 + e] : 0.f;

    // ---- MLP + likelihood, one px (16 depths) at a time ----
#pragma unroll
    for (int px = 0; px < 4; ++px) {
        f16x8 b0 = *(const f16x8*)&S[(w * 16 + n) * 136 + px * 32 + q * 8];
        // t1 const channel (ch48 = 1.0) + zero pad ch49..63
        {
            unsigned int lo = (q == 0) ? 0x00003C00u : 0u;
            *(uint2*)&t1s[n * 72 + 48 + q * 4] = make_uint2(lo, 0u);
        }
        // layer a: 26(+pad)->48
#pragma unroll
        for (int s = 0; s < 3; ++s) {
            f32x4 r1 = __builtin_amdgcn_mfma_f32_16x16x32_f16(waf[s], b0, zf, 0, 0, 0);
            *(uint2*)&t1s[n * 72 + s * 16 + q * 4] =
                make_uint2(pkrtz(fmaxf(r1[0], 0.f), fmaxf(r1[1], 0.f)),
                           pkrtz(fmaxf(r1[2], 0.f), fmaxf(r1[3], 0.f)));
        }
        // layer b: 48(+const)->96  (rb fully accumulated before t2 overwrites t1)
        f32x4 rb[6];
#pragma unroll
        for (int s = 0; s < 6; ++s) rb[s] = zf;
#pragma unroll
        for (int k2 = 0; k2 < 2; ++k2) {
            f16x8 bf = *(const f16x8*)&t1s[n * 72 + k2 * 32 + q * 8];
#pragma unroll
            for (int s = 0; s < 6; ++s)
                rb[s] = __builtin_amdgcn_mfma_f32_16x16x32_f16(wbf[s * 2 + k2], bf, rb[s], 0, 0, 0);
        }
#pragma unroll
        for (int s = 0; s < 6; ++s)
            *(uint2*)&t2s[n * 104 + s * 16 + q * 4] =
                make_uint2(pkrtz(fmaxf(rb[s][0], 0.f), fmaxf(rb[s][1], 0.f)),
                           pkrtz(fmaxf(rb[s][2], 0.f), fmaxf(rb[s][3], 0.f)));
        // layer c: 96->9
        f32x4 rc = zf;
#pragma unroll
        for (int k3 = 0; k3 < 3; ++k3) {
            f16x8 bf = *(const f16x8*)&t2s[n * 104 + k3 * 32 + q * 8];
            rc = __builtin_amdgcn_mfma_f32_16x16x32_f16(wcf[k3], bf, rc, 0, 0, 0);
        }
        // oacs overlays t2 (reads done above, same-wave order)
#pragma unroll
        for (int e = 0; e < 4; ++e) {
            int row = q * 4 + e;
            if (row < 9) oacs[n * 13 + row] = rc[e] + bcv[e];
        }
        // likelihood: lanes 0..15, one depth each
        if (lane < 16) {
            float o[9];
#pragma unroll
            for (int jj = 0; jj < 9; ++jj) o[jj] = oacs[lane * 13 + jj];
            const size_t gp = (size_t)(d0 + lane) * HW + y0 * 48 + x0 + 4 * w + px;
            float xv = xg[gp];
            float m = fmaxf(o[6], fmaxf(o[7], o[8]));
            float e0 = expf(o[6] - m), e1 = expf(o[7] - m), e2 = expf(o[8] - m);
            float inv_es = 1.0f / (e0 + e1 + e2);
            float p = 0.f;
#pragma unroll
            for (int jj = 0; jj < 3; ++jj) {
                float mu = o[jj];
                float sc = o[3 + jj];
                sc = (sc == 0.0f) ? 1e-9f : sc;
                sc = fabsf(sc);
                float a = phi_f((xv + 0.5f - mu) / sc);
                float b = phi_f((xv - 0.5f - mu) / sc);
                float lik = fabsf(a - b);
                float wgt = ((jj == 0) ? e0 : (jj == 1) ? e1 : e2) * inv_es;
                p = fmaf(wgt, lik, p);
            }
            out[gp] = p;
#pragma unroll
            for (int jj = 0; jj < 9; ++jj) out[NPOS + (size_t)jj * NPOS + gp] = o[jj];
        }
    }
}

extern "C" void kernel_launch(void* const* d_in, const int* in_sizes, int n_in,
                              void* d_out, int out_size, void* d_ws, size_t ws_size,
                              hipStream_t stream) {
    const float* x     = (const float*)d_in[0];
    const float* hyper = (const float*)d_in[1];
    const float* W3    = (const float*)d_in[2];
    const float* b3    = (const float*)d_in[3];
    const float* W1    = (const float*)d_in[4];
    const float* b1    = (const float*)d_in[5];
    const float* Wa    = (const float*)d_in[6];
    const float* ba    = (const float*)d_in[7];
    const float* Wb    = (const float*)d_in[8];
    const float* bb    = (const float*)d_in[9];
    const float* Wc    = (const float*)d_in[10];
    const float* bc    = (const float*)d_in[11];
    float* out = (float*)d_out;

    unsigned short* hyperTp = (unsigned short*)d_ws;           // 960000 f16
    unsigned short* apack   = hyperTp + 960000;                // 663552 f16
    unsigned short* pk      = apack + 663552;                  // 40960 f16
    unsigned short* xhp     = pk + 40960;                      // 749824 f16 (padded x)

    prep_all<<<4433, 256, 0, stream>>>(hyper, W3, W1, Wa, ba, b1, Wb, bb, Wc, x,
                                       hyperTp, apack, pk, xhp);
    conv3d_mlp<<<dim3(3, 48, 12), 256, 0, stream>>>(xhp, pk, hyperTp, apack, b3,
                                                    x, bc, out);
}